// Round 1
// baseline (874.407 us; speedup 1.0000x reference)
//
#include <hip/hip_runtime.h>

// AttentionBlock: B=8, C=256, HW=4096, GROUPS=8.
// Pipeline: GN -> Xt[bn,c] bf16 -> QK gemm -> V gemm -> per/all-batch (S gemm,
// softmax, PV gemm) -> proj gemm (+bias+residual) -> d_out fp32.
// All matmuls: m97-style gemm_bt (A,B row-major K-contiguous), bf16 MFMA 16x16x32.

typedef __bf16 bf16x8 __attribute__((ext_vector_type(8)));
typedef float floatx4 __attribute__((ext_vector_type(4)));

constexpr int Bb = 8, Cc_ = 256, HW = 4096;
constexpr int BNT = Bb * HW; // 32768 total positions

__device__ __forceinline__ void load_lds16(const void* g, void* l) {
  __builtin_amdgcn_global_load_lds((const __attribute__((address_space(1))) void*)g,
                                   (__attribute__((address_space(3))) void*)l, 16, 0, 0);
}

// ---------------- GroupNorm ----------------
__global__ __launch_bounds__(256) void gn_stats(const float* __restrict__ x,
                                                float* __restrict__ stats) {
  // one block per (b,g): contiguous 32*4096 floats
  const float4* p = (const float4*)(x + (size_t)blockIdx.x * (32 * HW));
  float s = 0.f, ss = 0.f;
  for (int i = threadIdx.x; i < 32 * HW / 4; i += 256) {
    float4 v = p[i];
    s += v.x + v.y + v.z + v.w;
    ss += v.x * v.x + v.y * v.y + v.z * v.z + v.w * v.w;
  }
  for (int off = 32; off; off >>= 1) { s += __shfl_down(s, off); ss += __shfl_down(ss, off); }
  __shared__ float red[8];
  int wave = threadIdx.x >> 6, lane = threadIdx.x & 63;
  if (lane == 0) { red[wave] = s; red[4 + wave] = ss; }
  __syncthreads();
  if (threadIdx.x == 0) {
    float S = red[0] + red[1] + red[2] + red[3];
    float SS = red[4] + red[5] + red[6] + red[7];
    float mean = S / (float)(32 * HW);
    float var = SS / (float)(32 * HW) - mean * mean;
    stats[blockIdx.x * 2] = mean;
    stats[blockIdx.x * 2 + 1] = rsqrtf(var + 1e-5f);
  }
}

__global__ __launch_bounds__(256) void gn_norm_t(const float* __restrict__ x,
                                                 const float* __restrict__ stats,
                                                 const float* __restrict__ gamma,
                                                 const float* __restrict__ beta,
                                                 __bf16* __restrict__ Xt) {
  // tile transpose: x[b][c][n] -> Xt[(b*HW+n)][c] bf16, 64x64 tiles
  __shared__ float tile[64][65];
  int b = blockIdx.z, c0 = blockIdx.y * 64, n0 = blockIdx.x * 64;
  int tid = threadIdx.x;
  int cl = tid >> 4, nl = (tid & 15) * 4;
  const float* xb = x + ((size_t)b * Cc_ + c0) * HW + n0;
#pragma unroll
  for (int i = 0; i < 4; ++i) {
    int c = cl + i * 16;
    float4 v = *(const float4*)&xb[(size_t)c * HW + nl];
    tile[c][nl] = v.x; tile[c][nl + 1] = v.y; tile[c][nl + 2] = v.z; tile[c][nl + 3] = v.w;
  }
  __syncthreads();
#pragma unroll
  for (int i = 0; i < 16; ++i) {
    int idx = i * 256 + tid;
    int n = idx >> 6, c = idx & 63;
    int gc = c0 + c;
    int grp = gc >> 5;
    float mean = stats[(b * 8 + grp) * 2], rstd = stats[(b * 8 + grp) * 2 + 1];
    float v = (tile[c][n] - mean) * rstd * gamma[gc] + beta[gc];
    Xt[((size_t)b * HW + n0 + n) * Cc_ + gc] = (__bf16)v;
  }
}

// ---------------- weight packing ----------------
__global__ __launch_bounds__(256) void pack_w(const float* __restrict__ wq, const float* __restrict__ wk,
                                              const float* __restrict__ wv, const float* __restrict__ wp,
                                              const float* __restrict__ bq, const float* __restrict__ bk,
                                              const float* __restrict__ bv, const float* __restrict__ bp,
                                              __bf16* __restrict__ Wqk, __bf16* __restrict__ Wv,
                                              __bf16* __restrict__ Wp, float* __restrict__ Bqk,
                                              float* __restrict__ Bv, float* __restrict__ Bp) {
  int i = blockIdx.x * 256 + threadIdx.x;
  if (i < 65536) {
    Wqk[i] = (__bf16)wq[i];
    Wqk[65536 + i] = (__bf16)wk[i];
    Wv[i] = (__bf16)wv[i];
    Wp[i] = (__bf16)wp[i];
  }
  if (i < 256) { Bqk[i] = bq[i]; Bqk[256 + i] = bk[i]; Bv[i] = bv[i]; Bp[i] = bp[i]; }
}

// ---------------- softmax (row-wise, in place, row=4096 bf16) ----------------
__global__ __launch_bounds__(256) void softmax_rows(__bf16* __restrict__ S) {
  __bf16* row = S + (size_t)blockIdx.x * HW;
  int tid = threadIdx.x;
  int wave = tid >> 6, lane = tid & 63;
  __shared__ float red[8];
  bf16x8 a = *(const bf16x8*)&row[tid * 16];
  bf16x8 b = *(const bf16x8*)&row[tid * 16 + 8];
  float v[16];
#pragma unroll
  for (int i = 0; i < 8; ++i) { v[i] = (float)a[i]; v[8 + i] = (float)b[i]; }
  float m = -1e30f;
#pragma unroll
  for (int i = 0; i < 16; ++i) m = fmaxf(m, v[i]);
  for (int off = 32; off; off >>= 1) m = fmaxf(m, __shfl_down(m, off));
  if (lane == 0) red[wave] = m;
  __syncthreads();
  m = fmaxf(fmaxf(red[0], red[1]), fmaxf(red[2], red[3]));
  float s = 0.f;
#pragma unroll
  for (int i = 0; i < 16; ++i) { v[i] = __expf(v[i] - m); s += v[i]; }
  for (int off = 32; off; off >>= 1) s += __shfl_down(s, off);
  if (lane == 0) red[4 + wave] = s;
  __syncthreads();
  float inv = 1.f / (red[4] + red[5] + red[6] + red[7]);
  bf16x8 oa, ob;
#pragma unroll
  for (int i = 0; i < 8; ++i) { oa[i] = (__bf16)(v[i] * inv); ob[i] = (__bf16)(v[8 + i] * inv); }
  *(bf16x8*)&row[tid * 16] = oa;
  *(bf16x8*)&row[tid * 16 + 8] = ob;
}

// ---------------- gemm_bt: C[m,n] = scale * sum_k A[m,k]*B[n,k] (+epilogue) ---
// EPI: 0 = bf16 out (with scale), 1 = bf16 out + bias[col], 2 = bf16 out + bias[row],
//      3 = fp32 scatter to d_out: out[b, row, n] = v + bias[row] + resid, col=(b*4096+n)
template <int BM, int BN, int WM, int WN, int EPI>
__global__ __launch_bounds__(256) void gemm_bt(
    const __bf16* __restrict__ A, int lda, long sAz,
    const __bf16* __restrict__ B, int ldb, long sBz,
    __bf16* __restrict__ C, int ldc, long sCz,
    int K, float scale,
    const float* __restrict__ bias,
    const float* __restrict__ resid,
    float* __restrict__ outF) {
  constexpr int TM = WM / 16, TN = WN / 16;
  __shared__ __bf16 As[BM * 32];
  __shared__ __bf16 Bs[BN * 32];

  A += (size_t)blockIdx.z * sAz;
  B += (size_t)blockIdx.z * sBz;
  if constexpr (EPI != 3) C += (size_t)blockIdx.z * sCz;

  const int tid = threadIdx.x;
  const int wave = tid >> 6, lane = tid & 63;
  const int wr = wave >> 1, wc = wave & 1;
  const int quad = lane >> 4, l16 = lane & 15;
  const int m0 = blockIdx.y * BM, n0 = blockIdx.x * BN;
  const int srow = lane >> 2;        // row within wave's 16-row staging chunk
  const int scol = (lane & 3) * 8;   // bf16 element offset (16B chunk)

  floatx4 acc[TM][TN] = {};

  const int kTiles = K / 32;
  for (int kt = 0; kt < kTiles; ++kt) {
    const int k0 = kt * 32;
    __syncthreads();
#pragma unroll
    for (int i = 0; i < BM / 64; ++i) {
      int row = i * 64 + wave * 16 + srow;
      load_lds16(A + (size_t)(m0 + row) * lda + k0 + scol, &As[(i * 64 + wave * 16) * 32]);
    }
#pragma unroll
    for (int i = 0; i < BN / 64; ++i) {
      int row = i * 64 + wave * 16 + srow;
      load_lds16(B + (size_t)(n0 + row) * ldb + k0 + scol, &Bs[(i * 64 + wave * 16) * 32]);
    }
    __syncthreads();

    bf16x8 af[TM], bfr[TN];
#pragma unroll
    for (int i = 0; i < TM; ++i)
      af[i] = *(const bf16x8*)&As[(wr * WM + i * 16 + l16) * 32 + quad * 8];
#pragma unroll
    for (int j = 0; j < TN; ++j)
      bfr[j] = *(const bf16x8*)&Bs[(wc * WN + j * 16 + l16) * 32 + quad * 8];
#pragma unroll
    for (int i = 0; i < TM; ++i)
#pragma unroll
      for (int j = 0; j < TN; ++j)
        acc[i][j] = __builtin_amdgcn_mfma_f32_16x16x32_bf16(af[i], bfr[j], acc[i][j], 0, 0, 0);
  }

#pragma unroll
  for (int i = 0; i < TM; ++i) {
#pragma unroll
    for (int j = 0; j < TN; ++j) {
      int gc = n0 + wc * WN + j * 16 + l16;
#pragma unroll
      for (int r = 0; r < 4; ++r) {
        int gr = m0 + wr * WM + i * 16 + quad * 4 + r;
        float v = acc[i][j][r] * scale;
        if constexpr (EPI == 1) v += bias[gc];
        if constexpr (EPI == 2) v += bias[gr];
        if constexpr (EPI == 3) {
          int bb = gc >> 12, nn = gc & 4095;
          size_t oidx = (size_t)bb * (Cc_ * HW) + (size_t)gr * HW + nn;
          outF[oidx] = v + bias[gr] + resid[oidx];
        } else {
          C[(size_t)gr * ldc + gc] = (__bf16)v;
        }
      }
    }
  }
}

extern "C" void kernel_launch(void* const* d_in, const int* in_sizes, int n_in,
                              void* d_out, int out_size, void* d_ws, size_t ws_size,
                              hipStream_t stream) {
  const float* x = (const float*)d_in[0];
  const float* gamma = (const float*)d_in[1];
  const float* beta = (const float*)d_in[2];
  const float* wq = (const float*)d_in[3];
  const float* bq = (const float*)d_in[4];
  const float* wk = (const float*)d_in[5];
  const float* bk = (const float*)d_in[6];
  const float* wv = (const float*)d_in[7];
  const float* bv = (const float*)d_in[8];
  const float* wp = (const float*)d_in[9];
  const float* bp = (const float*)d_in[10];
  float* out = (float*)d_out;

  char* ws = (char*)d_ws;
  size_t off = 0;
  auto alloc = [&](size_t n) { size_t o = off; off = (off + n + 255) & ~(size_t)255; return o; };
  __bf16* XT = (__bf16*)(ws + alloc((size_t)BNT * Cc_ * 2));   // [32768][256]
  __bf16* QK = (__bf16*)(ws + alloc((size_t)BNT * 512 * 2));   // [32768][512] (q|k)
  __bf16* V  = (__bf16*)(ws + alloc((size_t)Cc_ * BNT * 2));   // [256][32768]
  __bf16* O  = (__bf16*)(ws + alloc((size_t)BNT * Cc_ * 2));   // [32768][256]
  __bf16* WQK = (__bf16*)(ws + alloc(512 * 256 * 2));
  __bf16* WV  = (__bf16*)(ws + alloc(256 * 256 * 2));
  __bf16* WP  = (__bf16*)(ws + alloc(256 * 256 * 2));
  float* BQK = (float*)(ws + alloc(512 * 4));
  float* BV  = (float*)(ws + alloc(256 * 4));
  float* BP  = (float*)(ws + alloc(256 * 4));
  float* ST  = (float*)(ws + alloc(64 * 2 * 4));
  size_t s_one = (size_t)HW * HW * 2;  // one batch of S/P, bf16, 33.5 MB
  bool batched = ws_size >= off + 8 * s_one;  // deterministic across calls
  __bf16* S = (__bf16*)(ws + off);

  pack_w<<<dim3(256), dim3(256), 0, stream>>>(wq, wk, wv, wp, bq, bk, bv, bp,
                                              WQK, WV, WP, BQK, BV, BP);
  gn_stats<<<dim3(64), dim3(256), 0, stream>>>(x, ST);
  gn_norm_t<<<dim3(64, 4, 8), dim3(256), 0, stream>>>(x, ST, gamma, beta, XT);

  // QK[bn][o] = sum_c XT[bn][c] * WQK[o][c] + bias[o]
  gemm_bt<128, 128, 64, 64, 1><<<dim3(512 / 128, BNT / 128, 1), dim3(256), 0, stream>>>(
      XT, 256, 0, WQK, 256, 0, QK, 512, 0, 256, 1.0f, BQK, nullptr, nullptr);
  // V[c][bn] = sum_k WV[c][k] * XT[bn][k] + bias[c]
  gemm_bt<128, 128, 64, 64, 2><<<dim3(BNT / 128, 256 / 128, 1), dim3(256), 0, stream>>>(
      WV, 256, 0, XT, 256, 0, V, BNT, 0, 256, 1.0f, BV, nullptr, nullptr);

  if (batched) {
    gemm_bt<128, 128, 64, 64, 0><<<dim3(32, 32, 8), dim3(256), 0, stream>>>(
        QK, 512, (long)HW * 512, QK + 256, 512, (long)HW * 512,
        S, HW, (long)HW * HW, 256, 0.0625f, nullptr, nullptr, nullptr);
    softmax_rows<<<dim3(8 * HW), dim3(256), 0, stream>>>(S);
    gemm_bt<128, 128, 64, 64, 0><<<dim3(256 / 128, HW / 128, 8), dim3(256), 0, stream>>>(
        S, HW, (long)HW * HW, V, BNT, (long)HW,
        O, 256, (long)HW * 256, HW, 1.0f, nullptr, nullptr, nullptr);
  } else {
    for (int b = 0; b < 8; ++b) {
      const __bf16* Qb = QK + (size_t)b * HW * 512;
      gemm_bt<128, 128, 64, 64, 0><<<dim3(32, 32, 1), dim3(256), 0, stream>>>(
          Qb, 512, 0, Qb + 256, 512, 0, S, HW, 0, 256, 0.0625f, nullptr, nullptr, nullptr);
      softmax_rows<<<dim3(HW), dim3(256), 0, stream>>>(S);
      gemm_bt<64, 64, 32, 32, 0><<<dim3(256 / 64, HW / 64, 1), dim3(256), 0, stream>>>(
          S, HW, 0, V + (size_t)b * HW, BNT, 0, O + (size_t)b * HW * 256, 256, 0,
          HW, 1.0f, nullptr, nullptr, nullptr);
    }
  }

  // out[b][o][n] = x + sum_c WP[o][c]*O[bn][c] + bp[o]
  gemm_bt<128, 128, 64, 64, 3><<<dim3(BNT / 128, 256 / 128, 1), dim3(256), 0, stream>>>(
      WP, 256, 0, O, 256, 0, nullptr, 0, 0, 256, 1.0f, BP, x, out);
}

// Round 2
// 536.737 us; speedup vs baseline: 1.6291x; 1.6291x over previous
//
#include <hip/hip_runtime.h>

// AttentionBlock: B=8, C=256, HW=4096, GROUPS=8.
// R1: two-stage GroupNorm stats (fix 68us latency-bound gn_stats) + flash-fused
// attention (QK^T -> online softmax -> PV in one kernel, no materialized S).
// All matmuls bt-form (A,B row-major K-contiguous), bf16 MFMA 16x16x32.

typedef __bf16 bf16x8 __attribute__((ext_vector_type(8)));
typedef float floatx4 __attribute__((ext_vector_type(4)));

constexpr int Bb = 8, Cc_ = 256, HW = 4096;
constexpr int BNT = Bb * HW; // 32768 total positions

__device__ __forceinline__ void load_lds16(const void* g, void* l) {
  __builtin_amdgcn_global_load_lds((const __attribute__((address_space(1))) void*)g,
                                   (__attribute__((address_space(3))) void*)l, 16, 0, 0);
}

// ---------------- GroupNorm: stage 1 partial sums ----------------
__global__ __launch_bounds__(256) void gn_part(const float* __restrict__ x,
                                               float* __restrict__ part) {
  // block = (b,g,sub): sub-chunk of 16384 floats of a 131072-float group
  int sub = blockIdx.x & 7;
  int bg = blockIdx.x >> 3;
  const float4* p = (const float4*)(x + (size_t)bg * 131072 + (size_t)sub * 16384);
  int tid = threadIdx.x;
  float s = 0.f, ss = 0.f;
#pragma unroll
  for (int i = 0; i < 16; ++i) {
    float4 v = p[i * 256 + tid];
    s += v.x + v.y + v.z + v.w;
    ss += v.x * v.x + v.y * v.y + v.z * v.z + v.w * v.w;
  }
  for (int off = 32; off; off >>= 1) { s += __shfl_down(s, off); ss += __shfl_down(ss, off); }
  __shared__ float red[8];
  int wv = tid >> 6, ln = tid & 63;
  if (ln == 0) { red[wv] = s; red[4 + wv] = ss; }
  __syncthreads();
  if (tid == 0) {
    part[blockIdx.x * 2] = red[0] + red[1] + red[2] + red[3];
    part[blockIdx.x * 2 + 1] = red[4] + red[5] + red[6] + red[7];
  }
}

// ---------------- GroupNorm: normalize + transpose (finalize folded) --------
__global__ __launch_bounds__(256) void gn_norm_t(const float* __restrict__ x,
                                                 const float* __restrict__ part,
                                                 const float* __restrict__ gamma,
                                                 const float* __restrict__ beta,
                                                 __bf16* __restrict__ Xt) {
  __shared__ float tile[64][65];
  __shared__ float sst[4]; // {mean,rstd} x 2 groups
  int b = blockIdx.z, c0 = blockIdx.y * 64, n0 = blockIdx.x * 64;
  int tid = threadIdx.x;
  if (tid < 2) {
    int g = b * 8 + (c0 >> 5) + tid;
    float s = 0.f, ss = 0.f;
#pragma unroll
    for (int k = 0; k < 8; ++k) { s += part[(g * 8 + k) * 2]; ss += part[(g * 8 + k) * 2 + 1]; }
    float mean = s / 131072.f;
    float var = ss / 131072.f - mean * mean;
    sst[tid * 2] = mean;
    sst[tid * 2 + 1] = rsqrtf(var + 1e-5f);
  }
  int cl = tid >> 4, nl = (tid & 15) * 4;
  const float* xb = x + ((size_t)b * Cc_ + c0) * HW + n0;
#pragma unroll
  for (int i = 0; i < 4; ++i) {
    int c = cl + i * 16;
    float4 v = *(const float4*)&xb[(size_t)c * HW + nl];
    tile[c][nl] = v.x; tile[c][nl + 1] = v.y; tile[c][nl + 2] = v.z; tile[c][nl + 3] = v.w;
  }
  __syncthreads();
#pragma unroll
  for (int i = 0; i < 16; ++i) {
    int idx = i * 256 + tid;
    int n = idx >> 6, c = idx & 63;
    int gc = c0 + c;
    float mean = sst[(c >> 5) * 2], rstd = sst[(c >> 5) * 2 + 1];
    float v = (tile[c][n] - mean) * rstd * gamma[gc] + beta[gc];
    Xt[((size_t)b * HW + n0 + n) * Cc_ + gc] = (__bf16)v;
  }
}

// ---------------- weight packing ----------------
__global__ __launch_bounds__(256) void pack_w(const float* __restrict__ wq, const float* __restrict__ wk,
                                              const float* __restrict__ wv, const float* __restrict__ wp,
                                              const float* __restrict__ bq, const float* __restrict__ bk,
                                              const float* __restrict__ bv, const float* __restrict__ bp,
                                              __bf16* __restrict__ Wqk, __bf16* __restrict__ Wv,
                                              __bf16* __restrict__ Wp, float* __restrict__ Bqk,
                                              float* __restrict__ Bv, float* __restrict__ Bp) {
  int i = blockIdx.x * 256 + threadIdx.x;
  if (i < 65536) {
    Wqk[i] = (__bf16)wq[i];
    Wqk[65536 + i] = (__bf16)wk[i];
    Wv[i] = (__bf16)wv[i];
    Wp[i] = (__bf16)wp[i];
  }
  if (i < 256) { Bqk[i] = bq[i]; Bqk[256 + i] = bk[i]; Bv[i] = bv[i]; Bp[i] = bp[i]; }
}

// ---------------- gemm_bt: C[m,n] = scale*sum_k A[m,k]*B[n,k] (+epilogue) ----
// EPI: 1 = bf16 out + bias[col], 2 = bf16 out + bias[row],
//      3 = fp32 scatter: out[b,row,n] = v + bias[row] + resid, col=(b*4096+n)
template <int BM, int BN, int WM, int WN, int EPI>
__global__ __launch_bounds__(256) void gemm_bt(
    const __bf16* __restrict__ A, int lda,
    const __bf16* __restrict__ B, int ldb,
    __bf16* __restrict__ C, int ldc,
    int K, float scale,
    const float* __restrict__ bias,
    const float* __restrict__ resid,
    float* __restrict__ outF) {
  constexpr int TM = WM / 16, TN = WN / 16;
  __shared__ __bf16 As[BM * 32];
  __shared__ __bf16 Bs[BN * 32];

  const int tid = threadIdx.x;
  const int wave = tid >> 6, lane = tid & 63;
  const int wr = wave >> 1, wc = wave & 1;
  const int quad = lane >> 4, l16 = lane & 15;
  const int m0 = blockIdx.y * BM, n0 = blockIdx.x * BN;
  const int srow = lane >> 2;
  const int scol = (lane & 3) * 8;

  floatx4 acc[TM][TN] = {};

  const int kTiles = K / 32;
  for (int kt = 0; kt < kTiles; ++kt) {
    const int k0 = kt * 32;
    __syncthreads();
#pragma unroll
    for (int i = 0; i < BM / 64; ++i) {
      int row = i * 64 + wave * 16 + srow;
      load_lds16(A + (size_t)(m0 + row) * lda + k0 + scol, &As[(i * 64 + wave * 16) * 32]);
    }
#pragma unroll
    for (int i = 0; i < BN / 64; ++i) {
      int row = i * 64 + wave * 16 + srow;
      load_lds16(B + (size_t)(n0 + row) * ldb + k0 + scol, &Bs[(i * 64 + wave * 16) * 32]);
    }
    __syncthreads();

    bf16x8 af[TM], bfr[TN];
#pragma unroll
    for (int i = 0; i < TM; ++i)
      af[i] = *(const bf16x8*)&As[(wr * WM + i * 16 + l16) * 32 + quad * 8];
#pragma unroll
    for (int j = 0; j < TN; ++j)
      bfr[j] = *(const bf16x8*)&Bs[(wc * WN + j * 16 + l16) * 32 + quad * 8];
#pragma unroll
    for (int i = 0; i < TM; ++i)
#pragma unroll
      for (int j = 0; j < TN; ++j)
        acc[i][j] = __builtin_amdgcn_mfma_f32_16x16x32_bf16(af[i], bfr[j], acc[i][j], 0, 0, 0);
  }

#pragma unroll
  for (int i = 0; i < TM; ++i) {
#pragma unroll
    for (int j = 0; j < TN; ++j) {
      int gc = n0 + wc * WN + j * 16 + l16;
#pragma unroll
      for (int r = 0; r < 4; ++r) {
        int gr = m0 + wr * WM + i * 16 + quad * 4 + r;
        float v = acc[i][j][r] * scale;
        if constexpr (EPI == 1) v += bias[gc];
        if constexpr (EPI == 2) v += bias[gr];
        if constexpr (EPI == 3) {
          int bb = gc >> 12, nn = gc & 4095;
          size_t oidx = (size_t)bb * (Cc_ * HW) + (size_t)gr * HW + nn;
          outF[oidx] = v + bias[gr] + resid[oidx];
        } else {
          C[(size_t)gr * ldc + gc] = (__bf16)v;
        }
      }
    }
  }
}

// ---------------- flash attention ----------------
// Block: 64 Q-rows of one batch. Waves 4x1: wave owns 16 S-rows (softmax state
// wave-local; P round-trip wave-local). K,V tiles (64 cols) staged via
// global_load_lds with XOR-swizzled 16B chunks (breaks 512B/128B-stride bank
// conflicts). Q frags live in registers, pre-scaled by 1/16 (exact, pow2).
__global__ __launch_bounds__(256) void flash_attn(const __bf16* __restrict__ QK,
                                                  const __bf16* __restrict__ V,
                                                  __bf16* __restrict__ O) {
  __shared__ __align__(16) __bf16 Ks[64 * 256];   // [j_loc][c], chunk-swizzled
  __shared__ __align__(16) __bf16 Vt[256 * 64];   // [c][j_loc], chunk-swizzled
  __shared__ __align__(16) __bf16 Pw[4][16 * 72]; // per-wave P, row stride 72

  const int tid = threadIdx.x;
  const int w = tid >> 6, lane = tid & 63;
  const int quad = lane >> 4, l16 = lane & 15;
  const int b = blockIdx.z;
  const int m0 = blockIdx.x * 64;

  // Q fragments (A-operand): row = m0 + w*16 + l16, k = kc*32 + quad*8
  bf16x8 af[8];
  {
    const size_t qrow = (size_t)(b * HW + m0 + w * 16 + l16);
#pragma unroll
    for (int kc = 0; kc < 8; ++kc) {
      af[kc] = *(const bf16x8*)&QK[qrow * 512 + kc * 32 + quad * 8];
#pragma unroll
      for (int e = 0; e < 8; ++e) af[kc][e] = (__bf16)((float)af[kc][e] * 0.0625f);
    }
  }

  floatx4 oacc[16] = {};
  float mrow[4], lrow[4];
#pragma unroll
  for (int r = 0; r < 4; ++r) { mrow[r] = -1e30f; lrow[r] = 0.f; }

  const int ks_row_in = lane >> 5;  // 0..1 (rows of 512B)
  const int ks_slot = lane & 31;    // 16B slot in row
  const int vt_row_in = lane >> 3;  // 0..7 (rows of 128B)
  const int vt_slot = lane & 7;

  for (int jt = 0; jt < 64; ++jt) {
    const int j0 = jt * 64;
    __syncthreads();  // prev iter's LDS reads complete
#pragma unroll
    for (int i = 0; i < 8; ++i) {
      int rl = w * 16 + i * 2 + ks_row_in;
      int ch = ks_slot ^ (rl & 7);
      load_lds16(QK + (size_t)(b * HW + j0 + rl) * 512 + 256 + ch * 8,
                 &Ks[(w * 16 + i * 2) * 256]);
    }
#pragma unroll
    for (int i = 0; i < 8; ++i) {
      int cl = w * 64 + i * 8 + vt_row_in;
      int ch = vt_slot ^ (cl & 7);
      load_lds16(V + (size_t)cl * BNT + (b * HW + j0 + ch * 8),
                 &Vt[(w * 64 + i * 8) * 64]);
    }
    __syncthreads();  // staging complete

    // S-tile (16 rows x 64 cols) = Qs . K^T
    floatx4 sacc[4] = {};
#pragma unroll
    for (int kc = 0; kc < 8; ++kc) {
#pragma unroll
      for (int j = 0; j < 4; ++j) {
        int jl = j * 16 + l16;
        int ch = kc * 4 + quad;
        bf16x8 kf = *(const bf16x8*)&Ks[jl * 256 + (ch ^ (jl & 7)) * 8];
        sacc[j] = __builtin_amdgcn_mfma_f32_16x16x32_bf16(af[kc], kf, sacc[j], 0, 0, 0);
      }
    }

    // online softmax (rows = quad*4+r, wave-local; reduce across l16)
    float alpha[4];
    float p[4][4];
#pragma unroll
    for (int r = 0; r < 4; ++r) {
      float mx = fmaxf(fmaxf(sacc[0][r], sacc[1][r]), fmaxf(sacc[2][r], sacc[3][r]));
#pragma unroll
      for (int msk = 1; msk < 16; msk <<= 1) mx = fmaxf(mx, __shfl_xor(mx, msk));
      float mn = fmaxf(mrow[r], mx);
      alpha[r] = __expf(mrow[r] - mn);
      mrow[r] = mn;
      float rs = 0.f;
#pragma unroll
      for (int j = 0; j < 4; ++j) { p[j][r] = __expf(sacc[j][r] - mn); rs += p[j][r]; }
#pragma unroll
      for (int msk = 1; msk < 16; msk <<= 1) rs += __shfl_xor(rs, msk);
      lrow[r] = lrow[r] * alpha[r] + rs;
    }
#pragma unroll
    for (int j = 0; j < 4; ++j)
#pragma unroll
      for (int r = 0; r < 4; ++r)
        Pw[w][(quad * 4 + r) * 72 + j * 16 + l16] = (__bf16)p[j][r];
#pragma unroll
    for (int t = 0; t < 16; ++t) {
#pragma unroll
      for (int r = 0; r < 4; ++r) oacc[t][r] *= alpha[r];
    }

    // O += P . V^T (A = P from wave-local LDS, B = Vt)
#pragma unroll
    for (int kc = 0; kc < 2; ++kc) {
      bf16x8 pf = *(const bf16x8*)&Pw[w][l16 * 72 + kc * 32 + quad * 8];
#pragma unroll
      for (int t = 0; t < 16; ++t) {
        int cl = t * 16 + l16;
        int ch = kc * 4 + quad;
        bf16x8 vf = *(const bf16x8*)&Vt[cl * 64 + (ch ^ (cl & 7)) * 8];
        oacc[t] = __builtin_amdgcn_mfma_f32_16x16x32_bf16(pf, vf, oacc[t], 0, 0, 0);
      }
    }
  }

  // epilogue: normalize, stage to LDS (reuse Ks), coalesced 16B stores
  __syncthreads();
  float inv[4];
#pragma unroll
  for (int r = 0; r < 4; ++r) inv[r] = 1.f / lrow[r];
  __bf16* Os = Ks;  // 64 x 256
#pragma unroll
  for (int t = 0; t < 16; ++t)
#pragma unroll
    for (int r = 0; r < 4; ++r)
      Os[(w * 16 + quad * 4 + r) * 256 + t * 16 + l16] = (__bf16)(oacc[t][r] * inv[r]);
  __syncthreads();
  const float4* src = (const float4*)Os;
  float4* dst = (float4*)(O + (size_t)(b * HW + m0) * 256);
#pragma unroll
  for (int i = 0; i < 8; ++i) dst[i * 256 + tid] = src[i * 256 + tid];
}

extern "C" void kernel_launch(void* const* d_in, const int* in_sizes, int n_in,
                              void* d_out, int out_size, void* d_ws, size_t ws_size,
                              hipStream_t stream) {
  const float* x = (const float*)d_in[0];
  const float* gamma = (const float*)d_in[1];
  const float* beta = (const float*)d_in[2];
  const float* wq = (const float*)d_in[3];
  const float* bq = (const float*)d_in[4];
  const float* wk = (const float*)d_in[5];
  const float* bk = (const float*)d_in[6];
  const float* wv = (const float*)d_in[7];
  const float* bv = (const float*)d_in[8];
  const float* wp = (const float*)d_in[9];
  const float* bp = (const float*)d_in[10];
  float* out = (float*)d_out;

  char* ws = (char*)d_ws;
  size_t off = 0;
  auto alloc = [&](size_t n) { size_t o = off; off = (off + n + 255) & ~(size_t)255; return o; };
  __bf16* XT = (__bf16*)(ws + alloc((size_t)BNT * Cc_ * 2));   // [32768][256]
  __bf16* QK = (__bf16*)(ws + alloc((size_t)BNT * 512 * 2));   // [32768][512] (q|k)
  __bf16* V  = (__bf16*)(ws + alloc((size_t)Cc_ * BNT * 2));   // [256][32768]
  __bf16* O  = (__bf16*)(ws + alloc((size_t)BNT * Cc_ * 2));   // [32768][256]
  __bf16* WQK = (__bf16*)(ws + alloc(512 * 256 * 2));
  __bf16* WV  = (__bf16*)(ws + alloc(256 * 256 * 2));
  __bf16* WP  = (__bf16*)(ws + alloc(256 * 256 * 2));
  float* BQK = (float*)(ws + alloc(512 * 4));
  float* BV  = (float*)(ws + alloc(256 * 4));
  float* BP  = (float*)(ws + alloc(256 * 4));
  float* PART = (float*)(ws + alloc(512 * 2 * 4));

  pack_w<<<dim3(256), dim3(256), 0, stream>>>(wq, wk, wv, wp, bq, bk, bv, bp,
                                              WQK, WV, WP, BQK, BV, BP);
  gn_part<<<dim3(512), dim3(256), 0, stream>>>(x, PART);
  gn_norm_t<<<dim3(64, 4, 8), dim3(256), 0, stream>>>(x, PART, gamma, beta, XT);

  // QK[bn][o] = sum_c XT[bn][c] * WQK[o][c] + bias[o]
  gemm_bt<128, 128, 64, 64, 1><<<dim3(512 / 128, BNT / 128), dim3(256), 0, stream>>>(
      XT, 256, WQK, 256, QK, 512, 256, 1.0f, BQK, nullptr, nullptr);
  // V[c][bn] = sum_k WV[c][k] * XT[bn][k] + bias[c]
  gemm_bt<128, 128, 64, 64, 2><<<dim3(BNT / 128, 256 / 128), dim3(256), 0, stream>>>(
      WV, 256, XT, 256, V, BNT, 256, 1.0f, BV, nullptr, nullptr);

  // fused attention: O[bn][c]
  flash_attn<<<dim3(HW / 64, 1, Bb), dim3(256), 0, stream>>>(QK, V, O);

  // out[b][o][n] = x + sum_c WP[o][c]*O[bn][c] + bp[o]
  gemm_bt<128, 128, 64, 64, 3><<<dim3(BNT / 128, 256 / 128), dim3(256), 0, stream>>>(
      WP, 256, O, 256, nullptr, 0, 256, 1.0f, BP, x, out);
}